// Round 2
// baseline (3793.457 us; speedup 1.0000x reference)
//
#include <hip/hip_runtime.h>

#define T_LEN 16384
#define BATCH 32
#define HID 32
#define L2E 1.44269504088896340736f
#define SCLG (-2.0f * 1.44269504088896340736f)   // -2*log2e

typedef float f2 __attribute__((ext_vector_type(2)));
typedef unsigned u2_t __attribute__((ext_vector_type(2)));

#if __has_builtin(__builtin_amdgcn_exp2f)
#define EXP2F(x) __builtin_amdgcn_exp2f(x)
#else
#define EXP2F(x) __exp2f(x)
#endif
#if __has_builtin(__builtin_amdgcn_rcpf)
#define RCPF(x) __builtin_amdgcn_rcpf(x)
#else
#define RCPF(x) (1.0f / (x))
#endif

__device__ __forceinline__ float rlane(float v, int lane) {
    return __int_as_float(__builtin_amdgcn_readlane(__float_as_int(v), lane));
}

// Cross-half exchange, VALU pipe. Convention verified r4/r5:
// builtin returns {vdst_new, vsrc_new}; for swap(a,b):
//   r.x = a with hi32<-b.lo32 ; r.y = b with lo32<-a.hi32.
__device__ __forceinline__ u2_t xswap32(unsigned a, unsigned b) {
#if __has_builtin(__builtin_amdgcn_permlane32_swap)
    return __builtin_amdgcn_permlane32_swap(a, b, false, false);
#else
    u2_t r;
    r.x = __shfl_xor(b, 32, 64);  // approximate fallback (not expected to be used)
    r.y = __shfl_xor(a, 32, 64);
    return r;
#endif
}

// DPP mov: ctrl must be a literal at each expansion site (unrolled loops ok).
#define DPP(v, ctrl) ((unsigned)__builtin_amdgcn_mov_dpp((int)(v), (ctrl), 0xF, 0xF, true))

// 32 gathered values stored as 16 even-aligned f2 pairs (pk_fma operands).
struct H32 {
    f2 p[16];
    __device__ __forceinline__ unsigned get(int i) const {
        return __float_as_uint((i & 1) ? p[i >> 1].y : p[i >> 1].x);
    }
    __device__ __forceinline__ void set(int i, unsigned u) {
        if (i & 1) p[i >> 1].y = __uint_as_float(u);
        else       p[i >> 1].x = __uint_as_float(u);
    }
};

// r18 allgather: VALU-pipe butterfly, replaces the hbuf LDS round trip.
// Stage order: dist-16 first (1 value: permlane16_swap + detected-polarity
// cndmask; ds_swizzle xor16 fallback), then quad xor1 (2 movs), quad xor2
// (4), row_ror:4 (8), row_ror:8 (16). 32 ops total, 5-stage chain.
// Rotation direction / swap row-pairing ambiguity is ABSORBED: the same
// network is run at init on payload j to learn the per-lane column
// permutation, and W is loaded pre-permuted to match. Coverage holds under
// either ror direction ({Q,Q+-1,Q+2,Q+2+-1} mod 4 = all quads).
__device__ __forceinline__ void gather32(H32& o, unsigned h0, bool selx) {
    unsigned p16;
#if __has_builtin(__builtin_amdgcn_permlane16_swap)
    {
        u2_t rr = __builtin_amdgcn_permlane16_swap(h0, h0, false, false);
        p16 = selx ? rr.x : rr.y;   // selx loop-invariant -> hoisted mask, 1 cndmask
    }
#else
    p16 = (unsigned)__builtin_amdgcn_ds_swizzle((int)h0, 0x401F);  // xor 16 (exact)
#endif
    o.set(0, h0);
    o.set(1, p16);
    #pragma unroll
    for (int k = 0; k < 2; ++k)  o.set(2 + k,  DPP(o.get(k), 0xB1));   // quad_perm [1,0,3,2] = xor1
    #pragma unroll
    for (int k = 0; k < 4; ++k)  o.set(4 + k,  DPP(o.get(k), 0x4E));   // quad_perm [2,3,0,1] = xor2
    #pragma unroll
    for (int k = 0; k < 8; ++k)  o.set(8 + k,  DPP(o.get(k), 0x124));  // row_ror:4
    #pragma unroll
    for (int k = 0; k < 16; ++k) o.set(16 + k, DPP(o.get(k), 0x128));  // row_ror:8
}

// r18 = r16 (3066us) with the h-broadcast moved to a VALU-pipe DPP/permlane
// butterfly (no LDS, no SGPR-hazard readlanes). r17 post-mortem: readlane
// broadcast = LDS + 70cyc (SGPR read hazards); this tree is ~32 full-rate
// VALU ops, 5-dependent-stage chain, and needs h valid in ALL 64 lanes --
// provided by a redundant tail (dual permlane32_swap: one swap ships u' up
// AND sf down; a second makes 2*sigma_o wave-valid; cS/h recurrence then
// computed identically in both halves at zero extra instruction width).
__global__ __launch_bounds__(64) __attribute__((amdgpu_waves_per_eu(1, 1)))
void lstm_seq_kernel(const float* __restrict__ x,
                     const float* __restrict__ W_ih,
                     const float* __restrict__ W_hh,
                     const float* __restrict__ b_ih,
                     const float* __restrict__ b_hh,
                     const float* __restrict__ W_out,
                     const float* __restrict__ b_out,
                     float* __restrict__ out)
{
    const int b    = blockIdx.x;
    const int lane = threadIdx.x;
    const int j    = lane & 31;
    const bool upper = (lane >= 32);

    // torch gate order in W_ih/W_hh rows: [0,32)=i [32,64)=f [64,96)=g [96,128)=o
    const int rowA = upper ? (32 + j) : j;        // f : i   (both sigmoid)
    const int rowB = upper ? (96 + j) : (64 + j); // o : g   (sigmoid : tanh)

    const float sclA = -L2E;
    const float sclB = upper ? -L2E : SCLG;

    // Detect permlane16_swap output polarity once (convention-proof).
    bool selx = false;
#if __has_builtin(__builtin_amdgcn_permlane16_swap)
    {
        u2_t rr = __builtin_amdgcn_permlane16_swap((unsigned)lane, (unsigned)lane,
                                                   false, false);
        selx = (rr.x == (unsigned)(lane ^ 16));
    }
#endif

    // Learn the gather network's per-lane column permutation on payload j.
    H32 cols;
    gather32(cols, (unsigned)j, selx);

    // W rows loaded pre-permuted to match the gather order (scalar loads,
    // init-only), pre-scaled, pinned resident (r9/r12).
    f2 Wa2[16], Wb2[16];
    #pragma unroll
    for (int q = 0; q < 16; ++q) {
        const int c0 = (int)cols.get(2 * q);
        const int c1 = (int)cols.get(2 * q + 1);
        Wa2[q].x = W_hh[rowA * HID + c0] * sclA;
        Wa2[q].y = W_hh[rowA * HID + c1] * sclA;
        Wb2[q].x = W_hh[rowB * HID + c0] * sclB;
        Wb2[q].y = W_hh[rowB * HID + c1] * sclB;
    }
    #pragma unroll
    for (int q = 0; q < 16; ++q) { asm("" : "+v"(Wa2[q]), "+v"(Wb2[q])); }

    const float wihA = sclA * W_ih[rowA];
    const float wihB = sclB * W_ih[rowB];
    const float bA = sclA * (b_ih[rowA] + b_hh[rowA]);
    const float bB = sclB * (b_ih[rowB] + b_hh[rowB]);

    const float wout = W_out[j];
    const float bout = b_out[0];

    // phist[s][lane], stride 65: store banks (s+l)%32 conflict-free;
    // flush read phist[l*65+32+k] banks (l+k)%32 conflict-free.
    __shared__ float phist[64 * 65];

    float cS = 0.0f;     // cS = -2log2e * c, now maintained in ALL lanes

    // h gathered state (previous step's h, permuted per cols). h_0 = 0.
    H32 hs;
    #pragma unroll
    for (int q = 0; q < 16; ++q) hs.p[q] = (f2){0.0f, 0.0f};

    const float* xb = x + (size_t)b * T_LEN;
    float*       yb = out + (size_t)b * T_LEN;

    float xv = xb[lane];  // 64 timesteps of x per lane-chunk

    for (int t0 = 0; t0 < T_LEN; t0 += 64) {
        float xv_next = (t0 + 64 < T_LEN) ? xb[t0 + 64 + lane] : 0.0f;

        #pragma unroll 4
        for (int s = 0; s < 64; ++s) {
            // x contribution: independent of h, schedules off-chain
            const float xs  = rlane(xv, s);
            const float xpA = fmaf(xs, wihA, bA);
            const float xpB = fmaf(xs, wihB, bB);

            // dots: 32 pure-VGPR v_pk_fma_f32 on the gathered pairs,
            // 4-way split accumulators; acc0 starts at {xp, 0}.
            f2 zA[4], zB[4];
            zA[0].x = xpA; zA[0].y = 0.0f;
            zB[0].x = xpB; zB[0].y = 0.0f;
            #pragma unroll
            for (int p = 0; p < 16; ++p) {
                if (p == 0) {
                    asm("v_pk_fma_f32 %0, %1, %2, %0"
                        : "+v"(zA[0]) : "v"(hs.p[0]), "v"(Wa2[0]));
                    asm("v_pk_fma_f32 %0, %1, %2, %0"
                        : "+v"(zB[0]) : "v"(hs.p[0]), "v"(Wb2[0]));
                } else if (p < 4) {
                    asm("v_pk_mul_f32 %0, %1, %2"
                        : "=v"(zA[p]) : "v"(hs.p[p]), "v"(Wa2[p]));
                    asm("v_pk_mul_f32 %0, %1, %2"
                        : "=v"(zB[p]) : "v"(hs.p[p]), "v"(Wb2[p]));
                } else {
                    asm("v_pk_fma_f32 %0, %1, %2, %0"
                        : "+v"(zA[p & 3]) : "v"(hs.p[p]), "v"(Wa2[p]));
                    asm("v_pk_fma_f32 %0, %1, %2, %0"
                        : "+v"(zB[p & 3]) : "v"(hs.p[p]), "v"(Wb2[p]));
                }
            }
            const f2 rA = (zA[0] + zA[1]) + (zA[2] + zA[3]);
            const f2 rB = (zB[0] + zB[1]) + (zB[2] + zB[3]);
            const float za = rA.x + rA.y;   // pre-scaled gate input
            const float zb = rB.x + rB.y;

            // A = sigmoid (i lower / f upper); r = (g-tanh-sig lower / o upper)
            const float A = RCPF(1.0f + EXP2F(za));
            const float r = RCPF(1.0f + EXP2F(zb));
            const float tgS = fmaf(r, 2.0f * SCLG, -SCLG);  // lower: -2log2e*tanh(g)
            const float so2 = r + r;                        // upper: 2*sigma_o

            // lower: u' = A*tgS = -2log2e*(si*tg)
            const float up = A * tgS;

            // Dual exchange makes the tail valid in ALL lanes:
            //  s1.x = A  with hi<-up.lo  (upper receives u')
            //  s1.y = up with lo<-A.hi   (lower receives sigma_f)
            //  s2.y = so2 with lo<-so2.hi (all lanes = 2*sigma_o)
            const u2_t s1 = xswap32(__float_as_uint(A), __float_as_uint(up));
            const u2_t s2 = xswap32(__float_as_uint(so2), __float_as_uint(so2));
            const float F    = upper ? A : __uint_as_float(s1.y);   // sigma_f
            const float U    = upper ? __uint_as_float(s1.x) : up;  // u'
            const float so2a = __uint_as_float(s2.y);               // 2*sigma_o

            // all lanes: cS = sf*cS + u'; h = so*tanh(c) = so2a*(r2-0.5)
            cS = fmaf(F, cS, U);
            const float r2 = RCPF(1.0f + EXP2F(cS));
            const float h  = so2a * (r2 - 0.5f);

            // VALU-pipe allgather of h for the next step's dot (no LDS).
            gather32(hs, __float_as_uint(h), selx);

            phist[s * 65 + lane] = h * wout;   // deferred output (off-chain)
        }

        __syncthreads();  // single wave: cheap; publish phist
        float a0 = bout, a1 = 0.0f, a2 = 0.0f, a3 = 0.0f;
        #pragma unroll
        for (int k = 0; k < HID; k += 4) {
            a0 += phist[lane * 65 + 32 + k];
            a1 += phist[lane * 65 + 33 + k];
            a2 += phist[lane * 65 + 34 + k];
            a3 += phist[lane * 65 + 35 + k];
        }
        yb[t0 + lane] = (a0 + a1) + (a2 + a3);
        __syncthreads();  // protect phist before next chunk rewrites it

        xv = xv_next;
    }
}

extern "C" void kernel_launch(void* const* d_in, const int* in_sizes, int n_in,
                              void* d_out, int out_size, void* d_ws, size_t ws_size,
                              hipStream_t stream) {
    const float* x     = (const float*)d_in[0];
    const float* W_ih  = (const float*)d_in[1];
    const float* W_hh  = (const float*)d_in[2];
    const float* b_ih  = (const float*)d_in[3];
    const float* b_hh  = (const float*)d_in[4];
    const float* W_out = (const float*)d_in[5];
    const float* b_out = (const float*)d_in[6];
    float* out = (float*)d_out;

    lstm_seq_kernel<<<BATCH, 64, 0, stream>>>(x, W_ih, W_hh, b_ih, b_hh,
                                              W_out, b_out, out);
}

// Round 4
// 3057.569 us; speedup vs baseline: 1.2407x; 1.2407x over previous
//
#include <hip/hip_runtime.h>

#define T_LEN 16384
#define BATCH 32
#define HID 32
#define L2E 1.44269504088896340736f
#define SCLG (-2.0f * 1.44269504088896340736f)   // -2*log2e

typedef float f2 __attribute__((ext_vector_type(2)));
typedef float f4 __attribute__((ext_vector_type(4)));
typedef unsigned u2_t __attribute__((ext_vector_type(2)));

#if __has_builtin(__builtin_amdgcn_exp2f)
#define EXP2F(x) __builtin_amdgcn_exp2f(x)
#else
#define EXP2F(x) __exp2f(x)
#endif
#if __has_builtin(__builtin_amdgcn_rcpf)
#define RCPF(x) __builtin_amdgcn_rcpf(x)
#else
#define RCPF(x) (1.0f / (x))
#endif

__device__ __forceinline__ float rlane(float v, int lane) {
    return __int_as_float(__builtin_amdgcn_readlane(__float_as_int(v), lane));
}

// Cross-half exchange (lower->upper), VALU pipe. Convention verified r4/r5:
// builtin returns {vdst_new, vsrc_new}; r.x has lanes 32-63 = old lanes 0-31.
__device__ __forceinline__ float xhalf_lo_to_hi(float v) {
#if __has_builtin(__builtin_amdgcn_permlane32_swap)
    u2_t r = __builtin_amdgcn_permlane32_swap(__float_as_uint(v), __float_as_uint(v),
                                              false, false);
    return __uint_as_float(r.x);
#else
    return __shfl_xor(v, 32, 64);
#endif
}

// r19 = r16 (3066us, the champion) + scheduling-slack trims. Bracket closed
// over broadcast flavors: LDS 450 cyc/step < readlane 520 (r17) < DPP 556
// (r18) -- the LDS round trip stays. Cycle model: LDS ~130 + dot ~80 +
// trans tail ~90 (2 exp2 + 2 rcp, structurally invariant -- exp2-split and
// merged-rcp algebra are chain-neutral, verified on paper) + publish ~10
// = ~310; measured 450 -> ~140 slack. Trims:
//  1. phist store deferred one iteration: issues AFTER the next step's
//     broadcast reads, so the in-order DS pipe doesn't queue the 16-read
//     burst behind it. (phist/hbuf are distinct __shared__ arrays -- alias
//     disambiguation is trivial, unlike r15's merged-buffer disaster.)
//  2. hbuf read as 8x ds_read_b128 (f4): halves DS issue slots in the
//     latency window; f2 halves of an f4 are aligned VGPR pairs, free.
//  3. unroll 8 (was 4): wider cross-iteration scheduling window.
// (r20 resubmit: round-3 bench died to container-acquisition infra failure;
// no measurement existed for this source, so it goes back unchanged.)
__global__ __launch_bounds__(64) __attribute__((amdgpu_waves_per_eu(1, 1)))
void lstm_seq_kernel(const float* __restrict__ x,
                     const float* __restrict__ W_ih,
                     const float* __restrict__ W_hh,
                     const float* __restrict__ b_ih,
                     const float* __restrict__ b_hh,
                     const float* __restrict__ W_out,
                     const float* __restrict__ b_out,
                     float* __restrict__ out)
{
    const int b    = blockIdx.x;
    const int lane = threadIdx.x;
    const int j    = lane & 31;
    const bool upper = (lane >= 32);

    // torch gate order in W_ih/W_hh rows: [0,32)=i [32,64)=f [64,96)=g [96,128)=o
    const int rowA = upper ? (32 + j) : j;        // f : i   (both sigmoid)
    const int rowB = upper ? (96 + j) : (64 + j); // o : g   (sigmoid : tanh)

    // Pre-scale: sigmoid rows by -L2E; tanh row (g, lower B) by -2*L2E.
    const float sclA = -L2E;
    const float sclB = upper ? -L2E : SCLG;

    // W rows as float2 pairs (pre-scaled), pinned resident (r9/r12)
    f2 Wa2[16], Wb2[16];
    const f2* ra2 = reinterpret_cast<const f2*>(W_hh + (size_t)rowA * HID);
    const f2* rb2 = reinterpret_cast<const f2*>(W_hh + (size_t)rowB * HID);
    #pragma unroll
    for (int q = 0; q < 16; ++q) { Wa2[q] = ra2[q] * sclA; Wb2[q] = rb2[q] * sclB; }
    #pragma unroll
    for (int q = 0; q < 16; ++q) { asm("" : "+v"(Wa2[q]), "+v"(Wb2[q])); }

    const float wihA = sclA * W_ih[rowA];
    const float wihB = sclB * W_ih[rowB];
    const float bA = sclA * (b_ih[rowA] + b_hh[rowA]);
    const float bB = sclB * (b_ih[rowB] + b_hh[rowB]);

    const float wout = W_out[j];
    const float bout = b_out[0];

    // phist[s][lane], stride 65: store banks (s+l)%32 conflict-free;
    // flush read phist[l*65+32+k] banks (l+k)%32 conflict-free.
    __shared__ float phist[64 * 65];
    // h-broadcast buffer: FIXED address, single writer per slot (r15 lesson)
    // -- slot per lane; upper 32 slots [32..63] hold h_j.
    __shared__ float hbuf[64];

    float cS = 0.0f;             // cS = -2log2e * c, state in upper lanes
    hbuf[lane] = 0.0f;           // seed h_0 = 0
    __syncthreads();

    const float* xb = x + (size_t)b * T_LEN;
    float*       yb = out + (size_t)b * T_LEN;
    // wave-uniform broadcast-read base (h values live at hbuf[32..63]),
    // read as f4 quads -> register quads whose f2 halves ARE pk operands.
    const f4* hb4 = reinterpret_cast<const f4*>(&hbuf[32]);

    float xv = xb[lane];   // 64 timesteps of x per lane-chunk
    float hw_pend = 0.0f;  // deferred phist value (h*wout from previous s)

    for (int t0 = 0; t0 < T_LEN; t0 += 64) {
        float xv_next = (t0 + 64 < T_LEN) ? xb[t0 + 64 + lane] : 0.0f;

        #pragma unroll 8
        for (int s = 0; s < 64; ++s) {
            // broadcast read FIRST: 8x ds_read_b128, wave-uniform,
            // conflict-free; issues right behind the hbuf write.
            f4 hq[8];
            #pragma unroll
            for (int p = 0; p < 8; ++p) hq[p] = hb4[p];

            // deferred phist store for step s-1: queues BEHIND the reads.
            if (s > 0) phist[(s - 1) * 65 + lane] = hw_pend;

            // x contribution: independent of h, schedules off-chain
            const float xs  = rlane(xv, s);
            const float xpA = fmaf(xs, wihA, bA);
            const float xpB = fmaf(xs, wihB, bB);

            // destructure f4 quads into aligned f2 pairs (register aliases)
            f2 hv2[16];
            #pragma unroll
            for (int p = 0; p < 8; ++p) {
                hv2[2 * p].x     = hq[p].x;
                hv2[2 * p].y     = hq[p].y;
                hv2[2 * p + 1].x = hq[p].z;
                hv2[2 * p + 1].y = hq[p].w;
            }

            // dots: 32 pure-VGPR v_pk_fma_f32, 4-way split accumulators;
            // accumulator 0 starts at {xp, 0} (x/bias folded in).
            f2 zA[4], zB[4];
            zA[0].x = xpA; zA[0].y = 0.0f;
            zB[0].x = xpB; zB[0].y = 0.0f;
            #pragma unroll
            for (int p = 0; p < 16; ++p) {
                if (p == 0) {
                    asm("v_pk_fma_f32 %0, %1, %2, %0"
                        : "+v"(zA[0]) : "v"(hv2[0]), "v"(Wa2[0]));
                    asm("v_pk_fma_f32 %0, %1, %2, %0"
                        : "+v"(zB[0]) : "v"(hv2[0]), "v"(Wb2[0]));
                } else if (p < 4) {
                    asm("v_pk_mul_f32 %0, %1, %2"
                        : "=v"(zA[p]) : "v"(hv2[p]), "v"(Wa2[p]));
                    asm("v_pk_mul_f32 %0, %1, %2"
                        : "=v"(zB[p]) : "v"(hv2[p]), "v"(Wb2[p]));
                } else {
                    asm("v_pk_fma_f32 %0, %1, %2, %0"
                        : "+v"(zA[p & 3]) : "v"(hv2[p]), "v"(Wa2[p]));
                    asm("v_pk_fma_f32 %0, %1, %2, %0"
                        : "+v"(zB[p & 3]) : "v"(hv2[p]), "v"(Wb2[p]));
                }
            }
            const f2 rA = (zA[0] + zA[1]) + (zA[2] + zA[3]);
            const f2 rB = (zB[0] + zB[1]) + (zB[2] + zB[3]);
            const float za = rA.x + rA.y;   // pre-scaled gate input
            const float zb = rB.x + rB.y;

            // A = sigmoid (i lower / f upper): rcp(1+exp2(za))
            const float A = RCPF(1.0f + EXP2F(za));
            const float r = RCPF(1.0f + EXP2F(zb));
            // lower: tgS = -2log2e*tanh(g) = fma(r, 2SCLG, -SCLG)
            const float tgS = fmaf(r, 2.0f * SCLG, -SCLG);
            const float so2 = r + r;               // 2*so (upper), off-chain

            // lower: u' = A*tgS = -2log2e*(si*tg); ship to upper (VALU swap)
            const float up = A * tgS;
            const float tu = xhalf_lo_to_hi(up);

            // upper: cS = sf*cS + u'; tanh(c) via exp2(cS) direct
            cS = fmaf(A, cS, tu);
            const float r2 = RCPF(1.0f + EXP2F(cS));
            const float h  = fmaf(so2, r2, -r);    // so*tanh(c)

            hbuf[lane] = h;        // publish FIRST (gates next step)
            hw_pend = h * wout;    // phist store deferred to next iteration
        }

        phist[63 * 65 + lane] = hw_pend;   // last step of the chunk

        __syncthreads();  // single wave: cheap; publish phist
        float a0 = bout, a1 = 0.0f, a2 = 0.0f, a3 = 0.0f;
        #pragma unroll
        for (int k = 0; k < HID; k += 4) {
            a0 += phist[lane * 65 + 32 + k];
            a1 += phist[lane * 65 + 33 + k];
            a2 += phist[lane * 65 + 34 + k];
            a3 += phist[lane * 65 + 35 + k];
        }
        yb[t0 + lane] = (a0 + a1) + (a2 + a3);
        __syncthreads();  // protect phist before next chunk rewrites it

        xv = xv_next;
    }
}

extern "C" void kernel_launch(void* const* d_in, const int* in_sizes, int n_in,
                              void* d_out, int out_size, void* d_ws, size_t ws_size,
                              hipStream_t stream) {
    const float* x     = (const float*)d_in[0];
    const float* W_ih  = (const float*)d_in[1];
    const float* W_hh  = (const float*)d_in[2];
    const float* b_ih  = (const float*)d_in[3];
    const float* b_hh  = (const float*)d_in[4];
    const float* W_out = (const float*)d_in[5];
    const float* b_out = (const float*)d_in[6];
    float* out = (float*)d_out;

    lstm_seq_kernel<<<BATCH, 64, 0, stream>>>(x, W_ih, W_hh, b_ih, b_hh,
                                              W_out, b_out, out);
}